// Round 3
// baseline (482.343 us; speedup 1.0000x reference)
//
#include <hip/hip_runtime.h>

#pragma clang fp contract(off)

namespace {
constexpr int NB = 2, ND = 100, MH = 28, MW = 28;
constexpr int OH = 512, OW = 512;
constexpr int SH = 128, SW = 128, NC = 32;
constexpr int BMP_ROWS = 172, BMP_PW = 6, BMP_WORDS = BMP_ROWS * BMP_PW; // 1032 words/det

// workspace layout (int32 indices)
constexpr int OFF_COUNTS = 0;                    // NB*32
constexpr int OFF_AREA   = 64;                   // NB*ND
constexpr int OFF_YB     = OFF_AREA  + NB*ND;
constexpr int OFF_XB     = OFF_YB    + NB*ND;
constexpr int OFF_VAL    = OFF_XB    + NB*ND;
constexpr int OFF_FYMIN  = OFF_VAL   + NB*ND;    // float
constexpr int OFF_FXMIN  = OFF_FYMIN + NB*ND;    // float
constexpr int OFF_FHS    = OFF_FXMIN + NB*ND;    // float
constexpr int OFF_FWS    = OFF_FHS   + NB*ND;    // float
constexpr int OFF_SEGCLS = OFF_FWS   + NB*ND;    // bytes region: NB*OH*OW bytes
constexpr int OFF_BMP    = OFF_SEGCLS + (NB*OH*OW)/4; // uint words: NB*ND*BMP_WORDS
}

// ---------------- prep: sort + box bounds + zero counts ----------------
__global__ void k_prep(const float* __restrict__ boxes, const int* __restrict__ classes,
                       const float* __restrict__ scores, int* __restrict__ wsI) {
  const int b = blockIdx.x, t = threadIdx.x;
  float* wsF = (float*)wsI;
  __shared__ float s_sc[ND];
  __shared__ int s_ord[ND];
  if (t < ND) s_sc[t] = scores[b*ND + t];
  if (t < 32) wsI[OFF_COUNTS + b*32 + t] = 0;
  __syncthreads();
  if (t < ND) {
    float sn = s_sc[t];
    int r = 0;
    for (int j = 0; j < ND; ++j) {
      float sj = s_sc[j];
      r += (sj > sn) || (sj == sn && j < t);   // stable descending rank
    }
    s_ord[r] = t;
  }
  __syncthreads();
  if (t < ND) {
    int det = s_ord[t];
    int cls = classes[b*ND + det];
    float sc = s_sc[det];
    const float* bx = boxes + (size_t)(b*ND + det)*4;
    float ymin = bx[0], xmin = bx[1], ymax = bx[2], xmax = bx[3];
    bool keep = (sc > 0.5f) && (cls != 0);
    int ylo = (int)ceilf(ymin), yhi = (int)ceilf(ymax);
    int xlo = (int)ceilf(xmin), xhi = (int)ceilf(xmax);
    ylo = max(ylo, 0); xlo = max(xlo, 0);
    yhi = min(yhi, OH); xhi = min(xhi, OW);
    if (yhi < ylo) yhi = ylo;
    if (xhi < xlo) xhi = xlo;
    if (yhi - ylo > BMP_ROWS)   yhi = ylo + BMP_ROWS;   // safety (shouldn't trigger)
    if (xhi - xlo > BMP_PW*32)  xhi = xlo + BMP_PW*32;
    if (!keep) { yhi = ylo; xhi = xlo; }                // empty box -> empty mask
    float hs  = (ymax > ymin) ? (28.0f / (ymax - ymin)) : 0.0f;
    float wsc = (xmax > xmin) ? (28.0f / (xmax - xmin)) : 0.0f;
    int g = b*ND + t;
    wsI[OFF_YB  + g] = ylo | (yhi << 16);
    wsI[OFF_XB  + g] = xlo | (xhi << 16);
    wsI[OFF_VAL + g] = (det + 1) | (cls << 16);
    wsF[OFF_FYMIN + g] = ymin;
    wsF[OFF_FXMIN + g] = xmin;
    wsF[OFF_FHS   + g] = hs;
    wsF[OFF_FWS   + g] = wsc;
  }
}

// ---------------- seg: bilinear 128->512 resize + argmax + class counts + inst init ----------------
__global__ void k_seg(const float* __restrict__ seg, int* __restrict__ wsI,
                      int* __restrict__ out) {
  const int t = threadIdx.x;
  const int pid = blockIdx.x*256 + t;            // 0 .. NB*OH*OW-1
  const int b = pid >> 18;
  const int p = pid & (OH*OW - 1);
  const int y = p >> 9, x = p & (OW - 1);
  __shared__ unsigned int hist[NC];
  if (t < NC) hist[t] = 0u;
  __syncthreads();

  out[pid] = -1;                                 // init instance plane (scan paints over)

  float syf = ((float)y + 0.5f) * 0.25f - 0.5f;  // exact (eighths)
  float y0f = floorf(syf);
  float fy = syf - y0f;
  int y0 = (int)y0f, y1 = y0 + 1;
  if (y0 < 0)            { y0 = 0; y1 = 0; fy = 0.0f; }  // single tap, weight exactly 1
  else if (y1 > SH - 1)  { y1 = SH - 1; fy = 0.0f; }
  float sxf = ((float)x + 0.5f) * 0.25f - 0.5f;
  float x0f = floorf(sxf);
  float fx = sxf - x0f;
  int x0 = (int)x0f, x1 = x0 + 1;
  if (x0 < 0)            { x0 = 0; x1 = 0; fx = 0.0f; }
  else if (x1 > SW - 1)  { x1 = SW - 1; fx = 0.0f; }
  float wy = 1.0f - fy, wx = 1.0f - fx;

  const float4* p00 = (const float4*)(seg + ((size_t)(b*SH + y0)*SW + x0)*NC);
  const float4* p01 = (const float4*)(seg + ((size_t)(b*SH + y0)*SW + x1)*NC);
  const float4* p10 = (const float4*)(seg + ((size_t)(b*SH + y1)*SW + x0)*NC);
  const float4* p11 = (const float4*)(seg + ((size_t)(b*SH + y1)*SW + x1)*NC);
  float best = -3.4e38f;
  int bi = 0;
  #pragma unroll
  for (int cc = 0; cc < NC/4; ++cc) {
    float4 a = p00[cc], bb = p01[cc], c2 = p10[cc], d = p11[cc];
    float av[4] = {a.x, a.y, a.z, a.w};
    float bv[4] = {bb.x, bb.y, bb.z, bb.w};
    float cv[4] = {c2.x, c2.y, c2.z, c2.w};
    float dv[4] = {d.x, d.y, d.z, d.w};
    #pragma unroll
    for (int j = 0; j < 4; ++j) {
      float t0 = wy*av[j] + fy*cv[j];   // height pass first (matches XLA dim order)
      float t1 = wy*bv[j] + fy*dv[j];
      float v  = wx*t0 + fx*t1;
      int ch = cc*4 + j;
      if (v > best) { best = v; bi = ch; }  // strict > keeps first max (jnp.argmax)
    }
  }
  ((unsigned char*)wsI)[OFF_SEGCLS*4 + pid] = (unsigned char)bi;
  if (bi >= 2) atomicAdd(&hist[bi], 1u);
  __syncthreads();
  if (t < NC) {
    unsigned int h = hist[t];
    if (h) atomicAdd((unsigned int*)&wsI[OFF_COUNTS + b*32 + t], h);
  }
}

// ---------------- mask: per-det binary bitmap + area (no zero pass needed) ----------------
__global__ void k_mask(const float* __restrict__ dmasks, int* __restrict__ wsI) {
  const int g = blockIdx.x;       // b*ND + sorted k
  const int t = threadIdx.x;      // 256
  const float* wsF = (const float*)wsI;
  __shared__ float sm[MH*MW];
  __shared__ int s_area;
  const int yb = wsI[OFF_YB + g], xb = wsI[OFF_XB + g];
  const int ylo = yb & 0xffff, yhi = yb >> 16;
  const int xlo = xb & 0xffff, xhi = xb >> 16;
  const int rows = yhi - ylo, width = xhi - xlo;
  unsigned int* bmp = (unsigned int*)wsI + OFF_BMP + g*BMP_WORDS;
  if (t == 0) s_area = 0;
  if (rows <= 0 || width <= 0) {     // uniform branch
    if (t == 0) wsI[OFF_AREA + g] = 0;
    return;
  }
  const int det = (wsI[OFF_VAL + g] & 0xffff) - 1;
  const int b = g / ND;
  const float* mp = dmasks + (size_t)(b*ND + det)*(MH*MW);
  for (int i = t; i < MH*MW; i += 256) sm[i] = mp[i];
  const float ymin = wsF[OFF_FYMIN + g], xmin = wsF[OFF_FXMIN + g];
  const float hs = wsF[OFF_FHS + g], wsc = wsF[OFF_FWS + g];
  __syncthreads();
  const int words_x = (width + 31) >> 5;
  const int totalw = rows * words_x;
  const int bit = t & 31;
  for (int wi = (t >> 5); wi < totalw; wi += 8) {
    int r = wi / words_x;
    int w = wi - r*words_x;
    int y = ylo + r;
    int x = xlo + (w << 5) + bit;
    bool pred = false;
    if (x < xhi) {
      // exact op order of _paste_one (fp contract off)
      float ty = ((float)y + 0.5f); ty = ty - ymin; ty = ty * hs;  float my = ty - 0.5f;
      float tx = ((float)x + 0.5f); tx = tx - xmin; tx = tx * wsc; float mx = tx - 0.5f;
      float y0f = floorf(my), x0f = floorf(mx);
      float ly = my - y0f, lx = mx - x0f;
      int y0 = (int)y0f, x0 = (int)x0f;
      int y1 = min(max(y0 + 1, 0), MH - 1);
      int x1 = min(max(x0 + 1, 0), MW - 1);
      y0 = min(max(y0, 0), MH - 1);
      x0 = min(max(x0, 0), MW - 1);
      float v00 = sm[y0*MW + x0], v01 = sm[y0*MW + x1];
      float v10 = sm[y1*MW + x0], v11 = sm[y1*MW + x1];
      float omlx = 1.0f - lx, omly = 1.0f - ly;
      float top = omlx*v00 + lx*v01;
      float bot = omlx*v10 + lx*v11;
      float outv = omly*top + ly*bot;
      pred = outv > 0.5f;
    }
    unsigned long long m = __ballot(pred);
    unsigned int word = (t & 32) ? (unsigned int)(m >> 32) : (unsigned int)m;
    if (bit == 0) {
      bmp[r*BMP_PW + w] = word;
      if (word) atomicAdd(&s_area, __popc(word));
    }
  }
  __syncthreads();
  if (t == 0) wsI[OFF_AREA + g] = s_area;
}

// ---------------- scan: single-wave sequential overlap/accept + paint ----------------
__global__ void __launch_bounds__(64) k_scan(int* __restrict__ wsI, int* __restrict__ out) {
  const int b = blockIdx.x, t = threadIdx.x;   // 64 threads = 1 wave
  __shared__ unsigned int occ[OH*OW/32];       // 8192 words = 32KB canvas occupancy
  for (int i = t; i < OH*OW/32; i += 64) occ[i] = 0u;
  __syncthreads();
  int* __restrict__ outInst = out + b*(OH*OW);
  int* __restrict__ outCat  = out + NB*(OH*OW) + b*(OH*OW);
  for (int k = 0; k < ND; ++k) {
    const int g = b*ND + k;
    const int area = wsI[OFF_AREA + g];
    if (area <= 0) continue;                   // empty mask -> no effect (frac forced 0, bm empty)
    const int yb = wsI[OFF_YB + g], xb = wsI[OFF_XB + g];
    const int ylo = yb & 0xffff, xlo = xb & 0xffff;
    const int rows = (yb >> 16) - ylo;
    const int width = (xb >> 16) - xlo;
    const int words_x = (width + 31) >> 5;
    const int totalw = rows * words_x;
    const unsigned int* __restrict__ bmp = (const unsigned int*)wsI + OFF_BMP + g*BMP_WORDS;
    // pass 1: overlap = popcount(bm & occ)
    int cnt = 0;
    for (int wi = t; wi < totalw; wi += 64) {
      int r = wi / words_x, w = wi - r*words_x;
      unsigned int bm = bmp[r*BMP_PW + w];
      if (bm) {
        int gx0 = xlo + (w << 5);
        int q = gx0 >> 5, sh = gx0 & 31;
        int rb = (ylo + r) << 4;
        unsigned int o = occ[rb + q] >> sh;
        if (sh && q < 15) o |= occ[rb + q + 1] << (32 - sh);
        cnt += __popc(bm & o);
      }
    }
    #pragma unroll
    for (int off = 32; off > 0; off >>= 1) cnt += __shfl_xor(cnt, off);
    // uniform accept decision in every lane (no broadcast needed)
    const bool acc = ((float)cnt / (float)area) < 0.5f;   // area>=1 -> max(area,1)==area
    if (acc) {
      const int val = wsI[OFF_VAL + g];
      const int inst = val & 0xffff;
      const int cat  = val >> 16;
      // pass 2: new = bm & ~occ; occ |= new; paint new pixels
      for (int wi = t; wi < totalw; wi += 64) {
        int r = wi / words_x, w = wi - r*words_x;
        unsigned int bm = bmp[r*BMP_PW + w];
        if (!bm) continue;
        int gx0 = xlo + (w << 5);
        int q = gx0 >> 5, sh = gx0 & 31;
        int yy = ylo + r;
        int rb = yy << 4;
        unsigned int lo = bm << sh;
        unsigned int nw0 = lo & ~occ[rb + q];
        if (nw0) {
          atomicOr(&occ[rb + q], nw0);
          int rowbase = yy * OW + (q << 5);
          unsigned int m = nw0;
          while (m) {
            int bit = __ffs(m) - 1; m &= m - 1;
            outInst[rowbase + bit] = inst;
            outCat [rowbase + bit] = cat;
          }
        }
        if (sh && q < 15) {
          unsigned int hi = bm >> (32 - sh);
          unsigned int nw1 = hi & ~occ[rb + q + 1];
          if (nw1) {
            atomicOr(&occ[rb + q + 1], nw1);
            int rowbase = yy * OW + ((q + 1) << 5);
            unsigned int m = nw1;
            while (m) {
              int bit = __ffs(m) - 1; m &= m - 1;
              outInst[rowbase + bit] = inst;
              outCat [rowbase + bit] = cat;
            }
          }
        }
      }
    }
    __syncthreads();   // single-wave: cheap; enforces LDS ordering across dets
  }
}

// ---------------- final: stuff merge for unpainted pixels ----------------
__global__ void k_final(const int* __restrict__ wsI, int* __restrict__ out) {
  const int t = threadIdx.x;
  const int pid = blockIdx.x*256 + t;
  const int b = pid >> 18;
  __shared__ int s_cnt[NC];
  if (t < NC) s_cnt[t] = wsI[OFF_COUNTS + b*32 + t];
  __syncthreads();
  if (out[pid] == -1) {    // unpainted -> stuff (or void)
    int cls = ((const unsigned char*)wsI)[OFF_SEGCLS*4 + pid];
    int catf = (cls >= 2 && s_cnt[cls] > 4096) ? cls + 90 : 0;
    out[NB*OH*OW + pid] = catf;
  }
}

extern "C" void kernel_launch(void* const* d_in, const int* in_sizes, int n_in,
                              void* d_out, int out_size, void* d_ws, size_t ws_size,
                              hipStream_t stream) {
  const float* boxes   = (const float*)d_in[0];
  const int*   classes = (const int*)d_in[1];
  const float* scores  = (const float*)d_in[2];
  const float* dmasks  = (const float*)d_in[3];
  const float* seg     = (const float*)d_in[4];
  int* wsI = (int*)d_ws;
  int* out = (int*)d_out;

  k_prep<<<NB, 128, 0, stream>>>(boxes, classes, scores, wsI);
  k_seg <<<(NB*OH*OW)/256, 256, 0, stream>>>(seg, wsI, out);
  k_mask<<<NB*ND, 256, 0, stream>>>(dmasks, wsI);
  k_scan<<<NB, 64, 0, stream>>>(wsI, out);
  k_final<<<(NB*OH*OW)/256, 256, 0, stream>>>(wsI, out);
}

// Round 4
// 196.731 us; speedup vs baseline: 2.4518x; 2.4518x over previous
//
#include <hip/hip_runtime.h>

#pragma clang fp contract(off)

namespace {
constexpr int NB = 2, ND = 100, MH = 28, MW = 28;
constexpr int OH = 512, OW = 512;
constexpr int SH = 128, SW = 128, NC = 32;
constexpr int BMP_ROWS = 172, BMP_PW = 6, BMP_WORDS = BMP_ROWS * BMP_PW; // 1032 words/det

// workspace layout (int32 indices)
constexpr int OFF_COUNTS = 0;                    // NB*32
constexpr int OFF_AREA   = 64;                   // NB*ND
constexpr int OFF_ACC    = OFF_AREA  + NB*ND;
constexpr int OFF_YB     = OFF_ACC   + NB*ND;
constexpr int OFF_XB     = OFF_YB    + NB*ND;
constexpr int OFF_VAL    = OFF_XB    + NB*ND;
constexpr int OFF_FYMIN  = OFF_VAL   + NB*ND;    // float
constexpr int OFF_FXMIN  = OFF_FYMIN + NB*ND;    // float
constexpr int OFF_FHS    = OFF_FXMIN + NB*ND;    // float
constexpr int OFF_FWS    = OFF_FHS   + NB*ND;    // float
constexpr int OFF_SEGCLS = OFF_FWS   + NB*ND;    // bytes region: NB*OH*OW bytes
constexpr int OFF_BMP    = OFF_SEGCLS + (NB*OH*OW)/4; // uint words: NB*ND*BMP_WORDS (even -> 8B aligned)
constexpr int OCC_STRIDE = 17;                   // padded: odd stride -> bank-conflict-free row access
constexpr int OCC_WORDS  = OH*OCC_STRIDE + 32;   // +pad so unconditional 7-word window reads stay in-bounds
}

// ---------------- prep: sort + box bounds + zero counts ----------------
__global__ void k_prep(const float* __restrict__ boxes, const int* __restrict__ classes,
                       const float* __restrict__ scores, int* __restrict__ wsI) {
  const int b = blockIdx.x, t = threadIdx.x;
  float* wsF = (float*)wsI;
  __shared__ float s_sc[ND];
  __shared__ int s_ord[ND];
  if (t < ND) s_sc[t] = scores[b*ND + t];
  if (t < 32) wsI[OFF_COUNTS + b*32 + t] = 0;
  __syncthreads();
  if (t < ND) {
    float sn = s_sc[t];
    int r = 0;
    for (int j = 0; j < ND; ++j) {
      float sj = s_sc[j];
      r += (sj > sn) || (sj == sn && j < t);   // stable descending rank
    }
    s_ord[r] = t;
  }
  __syncthreads();
  if (t < ND) {
    int det = s_ord[t];
    int cls = classes[b*ND + det];
    float sc = s_sc[det];
    const float* bx = boxes + (size_t)(b*ND + det)*4;
    float ymin = bx[0], xmin = bx[1], ymax = bx[2], xmax = bx[3];
    bool keep = (sc > 0.5f) && (cls != 0);
    int ylo = (int)ceilf(ymin), yhi = (int)ceilf(ymax);
    int xlo = (int)ceilf(xmin), xhi = (int)ceilf(xmax);
    ylo = max(ylo, 0); xlo = max(xlo, 0);
    yhi = min(yhi, OH); xhi = min(xhi, OW);
    if (yhi < ylo) yhi = ylo;
    if (xhi < xlo) xhi = xlo;
    if (yhi - ylo > BMP_ROWS)   yhi = ylo + BMP_ROWS;   // safety (shouldn't trigger)
    if (xhi - xlo > BMP_PW*32)  xhi = xlo + BMP_PW*32;
    if (!keep) { yhi = ylo; xhi = xlo; }                // empty box -> empty mask
    float hs  = (ymax > ymin) ? (28.0f / (ymax - ymin)) : 0.0f;
    float wsc = (xmax > xmin) ? (28.0f / (xmax - xmin)) : 0.0f;
    int g = b*ND + t;
    wsI[OFF_YB  + g] = ylo | (yhi << 16);
    wsI[OFF_XB  + g] = xlo | (xhi << 16);
    wsI[OFF_VAL + g] = (det + 1) | (cls << 16);
    wsF[OFF_FYMIN + g] = ymin;
    wsF[OFF_FXMIN + g] = xmin;
    wsF[OFF_FHS   + g] = hs;
    wsF[OFF_FWS   + g] = wsc;
  }
}

// ---------------- seg: bilinear 128->512 resize + argmax + class counts ----------------
__global__ void k_seg(const float* __restrict__ seg, int* __restrict__ wsI) {
  const int t = threadIdx.x;
  const int pid = blockIdx.x*256 + t;            // 0 .. NB*OH*OW-1
  const int b = pid >> 18;
  const int p = pid & (OH*OW - 1);
  const int y = p >> 9, x = p & (OW - 1);
  __shared__ unsigned int hist[NC];
  if (t < NC) hist[t] = 0u;
  __syncthreads();

  float syf = ((float)y + 0.5f) * 0.25f - 0.5f;  // exact (eighths)
  float y0f = floorf(syf);
  float fy = syf - y0f;
  int y0 = (int)y0f, y1 = y0 + 1;
  if (y0 < 0)            { y0 = 0; y1 = 0; fy = 0.0f; }  // single tap, weight exactly 1
  else if (y1 > SH - 1)  { y1 = SH - 1; fy = 0.0f; }
  float sxf = ((float)x + 0.5f) * 0.25f - 0.5f;
  float x0f = floorf(sxf);
  float fx = sxf - x0f;
  int x0 = (int)x0f, x1 = x0 + 1;
  if (x0 < 0)            { x0 = 0; x1 = 0; fx = 0.0f; }
  else if (x1 > SW - 1)  { x1 = SW - 1; fx = 0.0f; }
  float wy = 1.0f - fy, wx = 1.0f - fx;

  const float4* p00 = (const float4*)(seg + ((size_t)(b*SH + y0)*SW + x0)*NC);
  const float4* p01 = (const float4*)(seg + ((size_t)(b*SH + y0)*SW + x1)*NC);
  const float4* p10 = (const float4*)(seg + ((size_t)(b*SH + y1)*SW + x0)*NC);
  const float4* p11 = (const float4*)(seg + ((size_t)(b*SH + y1)*SW + x1)*NC);
  float best = -3.4e38f;
  int bi = 0;
  #pragma unroll
  for (int cc = 0; cc < NC/4; ++cc) {
    float4 a = p00[cc], bb = p01[cc], c2 = p10[cc], d = p11[cc];
    float av[4] = {a.x, a.y, a.z, a.w};
    float bv[4] = {bb.x, bb.y, bb.z, bb.w};
    float cv[4] = {c2.x, c2.y, c2.z, c2.w};
    float dv[4] = {d.x, d.y, d.z, d.w};
    #pragma unroll
    for (int j = 0; j < 4; ++j) {
      float t0 = wy*av[j] + fy*cv[j];   // height pass first (matches XLA dim order)
      float t1 = wy*bv[j] + fy*dv[j];
      float v  = wx*t0 + fx*t1;
      int ch = cc*4 + j;
      if (v > best) { best = v; bi = ch; }  // strict > keeps first max (jnp.argmax)
    }
  }
  ((unsigned char*)wsI)[OFF_SEGCLS*4 + pid] = (unsigned char)bi;
  if (bi >= 2) atomicAdd(&hist[bi], 1u);
  __syncthreads();
  if (t < NC) {
    unsigned int h = hist[t];
    if (h) atomicAdd((unsigned int*)&wsI[OFF_COUNTS + b*32 + t], h);
  }
}

// ---------------- mask: per-det binary bitmap + area ----------------
__global__ void k_mask(const float* __restrict__ dmasks, int* __restrict__ wsI) {
  const int g = blockIdx.x;       // b*ND + sorted k
  const int t = threadIdx.x;      // 256
  const float* wsF = (const float*)wsI;
  __shared__ float sm[MH*MW];
  __shared__ int s_area;
  const int yb = wsI[OFF_YB + g], xb = wsI[OFF_XB + g];
  const int ylo = yb & 0xffff, yhi = yb >> 16;
  const int xlo = xb & 0xffff, xhi = xb >> 16;
  const int rows = yhi - ylo, width = xhi - xlo;
  unsigned int* bmp = (unsigned int*)wsI + OFF_BMP + g*BMP_WORDS;
  if (t == 0) s_area = 0;
  if (rows <= 0 || width <= 0) {     // uniform branch
    if (t == 0) wsI[OFF_AREA + g] = 0;
    return;
  }
  const int det = (wsI[OFF_VAL + g] & 0xffff) - 1;
  const int b = g / ND;
  const float* mp = dmasks + (size_t)(b*ND + det)*(MH*MW);
  for (int i = t; i < MH*MW; i += 256) sm[i] = mp[i];
  const float ymin = wsF[OFF_FYMIN + g], xmin = wsF[OFF_FXMIN + g];
  const float hs = wsF[OFF_FHS + g], wsc = wsF[OFF_FWS + g];
  __syncthreads();
  const int words_x = (width + 31) >> 5;
  const int totalw = rows * words_x;
  const int bit = t & 31;
  for (int wi = (t >> 5); wi < totalw; wi += 8) {
    int r = wi / words_x;
    int w = wi - r*words_x;
    int y = ylo + r;
    int x = xlo + (w << 5) + bit;
    bool pred = false;
    if (x < xhi) {
      // exact op order of _paste_one (fp contract off)
      float ty = ((float)y + 0.5f); ty = ty - ymin; ty = ty * hs;  float my = ty - 0.5f;
      float tx = ((float)x + 0.5f); tx = tx - xmin; tx = tx * wsc; float mx = tx - 0.5f;
      float y0f = floorf(my), x0f = floorf(mx);
      float ly = my - y0f, lx = mx - x0f;
      int y0 = (int)y0f, x0 = (int)x0f;
      int y1 = min(max(y0 + 1, 0), MH - 1);
      int x1 = min(max(x0 + 1, 0), MW - 1);
      y0 = min(max(y0, 0), MH - 1);
      x0 = min(max(x0, 0), MW - 1);
      float v00 = sm[y0*MW + x0], v01 = sm[y0*MW + x1];
      float v10 = sm[y1*MW + x0], v11 = sm[y1*MW + x1];
      float omlx = 1.0f - lx, omly = 1.0f - ly;
      float top = omlx*v00 + lx*v01;
      float bot = omlx*v10 + lx*v11;
      float outv = omly*top + ly*bot;
      pred = outv > 0.5f;
    }
    unsigned long long m = __ballot(pred);
    unsigned int word = (t & 32) ? (unsigned int)(m >> 32) : (unsigned int)m;
    if (bit == 0) {
      bmp[r*BMP_PW + w] = word;
      if (word) atomicAdd(&s_area, __popc(word));
    }
  }
  __syncthreads();
  if (t == 0) wsI[OFF_AREA + g] = s_area;
}

// ---------------- scan: single-wave, register-double-buffered bitmap pipeline ----------------
struct Bm { unsigned int w[3][6]; };

__device__ __forceinline__ void loadDet(const unsigned int* __restrict__ base, int kk, int t, Bm& d) {
  const unsigned int* p = base + kk*BMP_WORDS;
  #pragma unroll
  for (int j = 0; j < 3; ++j) {
    int rr = t + j*64; rr = (rr < BMP_ROWS) ? rr : (BMP_ROWS - 1);   // clamp, garbage masked later
    const uint2* rp = (const uint2*)(p + rr*BMP_PW);                 // 8B-aligned (stride 24B, even base)
    uint2 a = rp[0], bb = rp[1], c = rp[2];
    d.w[j][0] = a.x;  d.w[j][1] = a.y;
    d.w[j][2] = bb.x; d.w[j][3] = bb.y;
    d.w[j][4] = c.x;  d.w[j][5] = c.y;
  }
}

__device__ __forceinline__ void processDet(int t, const Bm& d, unsigned int* occ,
                                           int area, int yb, int xb, int* accp) {
  const int ylo = yb & 0xffff;
  const int rows = (yb >> 16) - ylo;
  const int xlo = xb & 0xffff;
  const int width = (xb >> 16) - xlo;
  const int words_x = (width + 31) >> 5;            // <= 6
  const int q0 = xlo >> 5, sh = xlo & 31;
  const int nw = (sh + width + 31) >> 5;            // canvas words per row, <= 7 (and q0+nw <= 16)
  unsigned int cw[3][7];
  int cnt = 0;
  #pragma unroll
  for (int j = 0; j < 3; ++j) {
    const int rr = t + j*64;
    const bool rv = rr < rows;
    unsigned int m[6];
    #pragma unroll
    for (int w = 0; w < 6; ++w)
      m[w] = (rv && (w < words_x)) ? d.w[j][w] : 0u;
    #pragma unroll
    for (int i = 0; i < 7; ++i) {
      unsigned int lo = (i < 6) ? (m[i] << sh) : 0u;
      unsigned int hi = (sh && i > 0) ? (m[i-1] >> (32 - sh)) : 0u;
      cw[j][i] = lo | hi;
    }
    const int rb = (ylo + (rv ? rr : 0)) * OCC_STRIDE;
    #pragma unroll
    for (int i = 0; i < 7; ++i) {
      unsigned int o = occ[rb + q0 + i];            // padded array: always in-bounds
      cnt += __popc(cw[j][i] & o & ((i < nw) ? 0xffffffffu : 0u));
    }
  }
  #pragma unroll
  for (int off = 32; off; off >>= 1) cnt += __shfl_xor(cnt, off);
  const bool acc = (area > 0) && ((float)cnt / (float)area < 0.5f);  // area>=1 -> max(area,1)==area
  if (t == 0) *accp = acc ? 1 : 0;
  if (acc) {
    #pragma unroll
    for (int j = 0; j < 3; ++j) {
      const int rr = t + j*64;
      if (rr < rows) {                              // rows disjoint per lane -> no atomics
        const int rb = (ylo + rr) * OCC_STRIDE;
        #pragma unroll
        for (int i = 0; i < 7; ++i)
          if (i < nw) occ[rb + q0 + i] |= cw[j][i];
      }
    }
  }
}

__global__ void __launch_bounds__(64) k_scan(int* __restrict__ wsI) {
  const int b = blockIdx.x, t = threadIdx.x;        // 64 threads = 1 wave: lockstep, no barriers
  __shared__ unsigned int occ[OCC_WORDS];
  __shared__ int s_area[ND], s_yb[ND], s_xb[ND];
  for (int i = t; i < OCC_WORDS; i += 64) occ[i] = 0u;
  for (int i = t; i < ND; i += 64) {
    s_area[i] = wsI[OFF_AREA + b*ND + i];
    s_yb[i]   = wsI[OFF_YB  + b*ND + i];
    s_xb[i]   = wsI[OFF_XB  + b*ND + i];
  }
  __syncthreads();
  const unsigned int* __restrict__ bmpB = (const unsigned int*)wsI + OFF_BMP + (size_t)b*ND*BMP_WORDS;
  int* accBase = wsI + OFF_ACC + b*ND;
  Bm A, B;
  loadDet(bmpB, 0, t, A);
  for (int k = 0; k < ND; k += 2) {                 // double-buffered: load k+1 while computing k
    loadDet(bmpB, (k+1 < ND) ? (k+1) : (ND-1), t, B);
    processDet(t, A, occ, s_area[k], s_yb[k], s_xb[k], accBase + k);
    loadDet(bmpB, (k+2 < ND) ? (k+2) : (ND-1), t, A);
    processDet(t, B, occ, s_area[k+1], s_yb[k+1], s_xb[k+1], accBase + k + 1);
  }
}

// ---------------- final: paint first accepted covering det per pixel + stuff merge ----------------
__global__ void k_final(const int* __restrict__ wsI, int* __restrict__ out) {
  const int t = threadIdx.x;
  const int pid = blockIdx.x*256 + t;
  const int b = pid >> 18;
  const int y = (pid >> 9) & (OH - 1);
  const int x = pid & (OW - 1);
  __shared__ unsigned int s_yb[ND], s_xb[ND], s_val[ND];
  __shared__ int s_cnt[NC];
  if (t < ND) {
    int g = b*ND + t;
    int acc = wsI[OFF_ACC + g];
    s_yb[t] = acc ? (unsigned int)wsI[OFF_YB + g] : 0u;   // 0 => empty range
    s_xb[t] = (unsigned int)wsI[OFF_XB + g];
    s_val[t] = (unsigned int)wsI[OFF_VAL + g];
  }
  if (t >= 128 && t < 128 + NC) s_cnt[t - 128] = wsI[OFF_COUNTS + b*32 + (t - 128)];
  __syncthreads();
  int inst = -1, cat = 0;
  const unsigned int yu = (unsigned int)y, xu = (unsigned int)x;
  const unsigned int* bmpAll = (const unsigned int*)wsI + OFF_BMP + b*ND*BMP_WORDS;
  for (int k = 0; k < ND; ++k) {
    unsigned int yb = s_yb[k];
    if (yu >= (yb & 0xffffu) && yu < (yb >> 16)) {
      unsigned int xb = s_xb[k];
      if (xu >= (xb & 0xffffu) && xu < (xb >> 16)) {
        int ylo = (int)(yb & 0xffffu), xlo = (int)(xb & 0xffffu);
        int cb = x - xlo;
        unsigned int word = bmpAll[k*BMP_WORDS + (y - ylo)*BMP_PW + (cb >> 5)];
        if ((word >> (cb & 31)) & 1u) {
          unsigned int val = s_val[k];
          inst = (int)(val & 0xffffu);
          cat  = (int)(val >> 16);
          break;
        }
      }
    }
  }
  int cls = ((const unsigned char*)wsI)[OFF_SEGCLS*4 + pid];
  int catf = cat;
  if (cat == 0 && cls >= 2 && s_cnt[cls] > 4096) catf = cls + 90;
  out[pid] = inst;
  out[NB*OH*OW + pid] = catf;
}

extern "C" void kernel_launch(void* const* d_in, const int* in_sizes, int n_in,
                              void* d_out, int out_size, void* d_ws, size_t ws_size,
                              hipStream_t stream) {
  const float* boxes   = (const float*)d_in[0];
  const int*   classes = (const int*)d_in[1];
  const float* scores  = (const float*)d_in[2];
  const float* dmasks  = (const float*)d_in[3];
  const float* seg     = (const float*)d_in[4];
  int* wsI = (int*)d_ws;
  int* out = (int*)d_out;

  k_prep<<<NB, 128, 0, stream>>>(boxes, classes, scores, wsI);
  k_seg <<<(NB*OH*OW)/256, 256, 0, stream>>>(seg, wsI);
  k_mask<<<NB*ND, 256, 0, stream>>>(dmasks, wsI);
  k_scan<<<NB, 64, 0, stream>>>(wsI);
  k_final<<<(NB*OH*OW)/256, 256, 0, stream>>>(wsI, out);
}

// Round 5
// 165.571 us; speedup vs baseline: 2.9132x; 1.1882x over previous
//
#include <hip/hip_runtime.h>

#pragma clang fp contract(off)

namespace {
constexpr int NB = 2, ND = 100, MH = 28, MW = 28;
constexpr int OH = 512, OW = 512;
constexpr int SH = 128, SW = 128, NC = 32;
constexpr int BMP_ROWS = 172;
constexpr int BMP8_ROWWORDS = 8;                       // pre-shifted canvas-aligned words/row
constexpr int BMP8_DETWORDS = BMP_ROWS * BMP8_ROWWORDS; // 1376 (mod 4 == 0 -> uint4 ok)

// workspace layout (int32 word indices)
constexpr int OFF_COUNTS = 0;                     // NB*32
constexpr int OFF_AREA   = 64;                    // NB*ND
constexpr int OFF_ACC    = OFF_AREA  + NB*ND;
constexpr int OFF_YB     = OFF_ACC   + NB*ND;
constexpr int OFF_XB     = OFF_YB    + NB*ND;
constexpr int OFF_VAL    = OFF_XB    + NB*ND;
constexpr int OFF_QN     = OFF_VAL   + NB*ND;     // q0 | (nw<<16)
constexpr int OFF_FYMIN  = OFF_QN    + NB*ND;     // float
constexpr int OFF_FXMIN  = OFF_FYMIN + NB*ND;     // float
constexpr int OFF_FHS    = OFF_FXMIN + NB*ND;     // float
constexpr int OFF_FWS    = OFF_FHS   + NB*ND;     // float
constexpr int OFF_SEGCLS = OFF_FWS   + NB*ND;     // byte region: NB*OH*OW bytes
constexpr int OFF_BMP8   = OFF_SEGCLS + (NB*OH*OW)/4;  // 133136, mod 4 == 0
constexpr int OCC_STRIDE = 25;                    // odd -> bank-conflict-free; words 16..24 = pad
constexpr int OCC_WORDS  = OH * OCC_STRIDE;       // 12800 words = 51.2 KB
static_assert(OFF_BMP8 % 4 == 0, "uint4 alignment");
}

// ---------------- prep: sort + box bounds + zero counts ----------------
__global__ void k_prep(const float* __restrict__ boxes, const int* __restrict__ classes,
                       const float* __restrict__ scores, int* __restrict__ wsI) {
  const int b = blockIdx.x, t = threadIdx.x;
  float* wsF = (float*)wsI;
  __shared__ float s_sc[ND];
  __shared__ int s_ord[ND];
  if (t < ND) s_sc[t] = scores[b*ND + t];
  if (t < 32) wsI[OFF_COUNTS + b*32 + t] = 0;
  __syncthreads();
  if (t < ND) {
    float sn = s_sc[t];
    int r = 0;
    for (int j = 0; j < ND; ++j) {
      float sj = s_sc[j];
      r += (sj > sn) || (sj == sn && j < t);   // stable descending rank
    }
    s_ord[r] = t;
  }
  __syncthreads();
  if (t < ND) {
    int det = s_ord[t];
    int cls = classes[b*ND + det];
    float sc = s_sc[det];
    const float* bx = boxes + (size_t)(b*ND + det)*4;
    float ymin = bx[0], xmin = bx[1], ymax = bx[2], xmax = bx[3];
    bool keep = (sc > 0.5f) && (cls != 0);
    int ylo = (int)ceilf(ymin), yhi = (int)ceilf(ymax);
    int xlo = (int)ceilf(xmin), xhi = (int)ceilf(xmax);
    ylo = max(ylo, 0); xlo = max(xlo, 0);
    yhi = min(yhi, OH); xhi = min(xhi, OW);
    if (yhi < ylo) yhi = ylo;
    if (xhi < xlo) xhi = xlo;
    if (yhi - ylo > BMP_ROWS) yhi = ylo + BMP_ROWS;     // safety
    if (xhi - xlo > 192)      xhi = xlo + 192;          // safety (6 raw words)
    if (!keep) { yhi = ylo; xhi = xlo; }                // empty box -> empty mask
    int width = xhi - xlo;
    int q0 = xlo >> 5;
    int nw = (width > 0) ? (((xlo & 31) + width + 31) >> 5) : 0;  // <= 7
    float hs  = (ymax > ymin) ? (28.0f / (ymax - ymin)) : 0.0f;
    float wsc = (xmax > xmin) ? (28.0f / (xmax - xmin)) : 0.0f;
    int g = b*ND + t;
    wsI[OFF_YB  + g] = ylo | (yhi << 16);
    wsI[OFF_XB  + g] = xlo | (xhi << 16);
    wsI[OFF_VAL + g] = (det + 1) | (cls << 16);
    wsI[OFF_QN  + g] = q0 | (nw << 16);
    wsF[OFF_FYMIN + g] = ymin;
    wsF[OFF_FXMIN + g] = xmin;
    wsF[OFF_FHS   + g] = hs;
    wsF[OFF_FWS   + g] = wsc;
  }
}

// ---------------- seg: bilinear 128->512 resize + argmax + class counts ----------------
__global__ void k_seg(const float* __restrict__ seg, int* __restrict__ wsI) {
  const int t = threadIdx.x;
  const int pid = blockIdx.x*256 + t;            // 0 .. NB*OH*OW-1
  const int b = pid >> 18;
  const int p = pid & (OH*OW - 1);
  const int y = p >> 9, x = p & (OW - 1);
  __shared__ unsigned int hist[NC];
  if (t < NC) hist[t] = 0u;
  __syncthreads();

  float syf = ((float)y + 0.5f) * 0.25f - 0.5f;  // exact (eighths)
  float y0f = floorf(syf);
  float fy = syf - y0f;
  int y0 = (int)y0f, y1 = y0 + 1;
  if (y0 < 0)            { y0 = 0; y1 = 0; fy = 0.0f; }  // single tap, weight exactly 1
  else if (y1 > SH - 1)  { y1 = SH - 1; fy = 0.0f; }
  float sxf = ((float)x + 0.5f) * 0.25f - 0.5f;
  float x0f = floorf(sxf);
  float fx = sxf - x0f;
  int x0 = (int)x0f, x1 = x0 + 1;
  if (x0 < 0)            { x0 = 0; x1 = 0; fx = 0.0f; }
  else if (x1 > SW - 1)  { x1 = SW - 1; fx = 0.0f; }
  float wy = 1.0f - fy, wx = 1.0f - fx;

  const float4* p00 = (const float4*)(seg + ((size_t)(b*SH + y0)*SW + x0)*NC);
  const float4* p01 = (const float4*)(seg + ((size_t)(b*SH + y0)*SW + x1)*NC);
  const float4* p10 = (const float4*)(seg + ((size_t)(b*SH + y1)*SW + x0)*NC);
  const float4* p11 = (const float4*)(seg + ((size_t)(b*SH + y1)*SW + x1)*NC);
  float best = -3.4e38f;
  int bi = 0;
  #pragma unroll
  for (int cc = 0; cc < NC/4; ++cc) {
    float4 a = p00[cc], bb = p01[cc], c2 = p10[cc], d = p11[cc];
    float av[4] = {a.x, a.y, a.z, a.w};
    float bv[4] = {bb.x, bb.y, bb.z, bb.w};
    float cv[4] = {c2.x, c2.y, c2.z, c2.w};
    float dv[4] = {d.x, d.y, d.z, d.w};
    #pragma unroll
    for (int j = 0; j < 4; ++j) {
      float t0 = wy*av[j] + fy*cv[j];   // height pass first (matches XLA dim order)
      float t1 = wy*bv[j] + fy*dv[j];
      float v  = wx*t0 + fx*t1;
      int ch = cc*4 + j;
      if (v > best) { best = v; bi = ch; }  // strict > keeps first max (jnp.argmax)
    }
  }
  ((unsigned char*)wsI)[OFF_SEGCLS*4 + pid] = (unsigned char)bi;
  if (bi >= 2) atomicAdd(&hist[bi], 1u);
  __syncthreads();
  if (t < NC) {
    unsigned int h = hist[t];
    if (h) atomicAdd((unsigned int*)&wsI[OFF_COUNTS + b*32 + t], h);
  }
}

// ---------------- mask: per-det canvas-aligned (pre-shifted) bitmap + area ----------------
__global__ void k_mask(const float* __restrict__ dmasks, int* __restrict__ wsI) {
  const int g = blockIdx.x;       // b*ND + sorted k
  const int t = threadIdx.x;      // 256 = 8 words x 32 bits
  const float* wsF = (const float*)wsI;
  __shared__ float sm[MH*MW];
  __shared__ int s_area;
  const int yb = wsI[OFF_YB + g], xb = wsI[OFF_XB + g];
  const int ylo = yb & 0xffff, yhi = yb >> 16;
  const int xlo = xb & 0xffff, xhi = xb >> 16;
  const int rows = yhi - ylo, width = xhi - xlo;
  if (t == 0) s_area = 0;
  if (rows <= 0 || width <= 0) {     // uniform: empty det, bitmap never read downstream
    if (t == 0) wsI[OFF_AREA + g] = 0;
    return;
  }
  const int q0 = wsI[OFF_QN + g] & 0xffff;
  const int det = (wsI[OFF_VAL + g] & 0xffff) - 1;
  const int b = g / ND;
  const float* mp = dmasks + (size_t)(b*ND + det)*(MH*MW);
  for (int i = t; i < MH*MW; i += 256) sm[i] = mp[i];
  const float ymin = wsF[OFF_FYMIN + g], xmin = wsF[OFF_FXMIN + g];
  const float hs = wsF[OFF_FHS + g], wsc = wsF[OFF_FWS + g];
  __syncthreads();
  unsigned int* bmp8 = (unsigned int*)wsI + OFF_BMP8 + g*BMP8_DETWORDS;
  const int iw = t >> 5, bit = t & 31;
  const int x = ((q0 + iw) << 5) + bit;          // canvas x for this lane's bit
  const bool inbox = (x >= xlo) && (x < xhi);
  for (int r = 0; r < rows; ++r) {
    const int y = ylo + r;
    bool pred = false;
    if (inbox) {
      // exact op order of _paste_one (fp contract off)
      float ty = ((float)y + 0.5f); ty = ty - ymin; ty = ty * hs;  float my = ty - 0.5f;
      float tx = ((float)x + 0.5f); tx = tx - xmin; tx = tx * wsc; float mx = tx - 0.5f;
      float y0f = floorf(my), x0f = floorf(mx);
      float ly = my - y0f, lx = mx - x0f;
      int y0 = (int)y0f, x0 = (int)x0f;
      int y1 = min(max(y0 + 1, 0), MH - 1);
      int x1 = min(max(x0 + 1, 0), MW - 1);
      y0 = min(max(y0, 0), MH - 1);
      x0 = min(max(x0, 0), MW - 1);
      float v00 = sm[y0*MW + x0], v01 = sm[y0*MW + x1];
      float v10 = sm[y1*MW + x0], v11 = sm[y1*MW + x1];
      float omlx = 1.0f - lx, omly = 1.0f - ly;
      float top = omlx*v00 + lx*v01;
      float bot = omlx*v10 + lx*v11;
      float outv = omly*top + ly*bot;
      pred = outv > 0.5f;
    }
    unsigned long long m = __ballot(pred);
    unsigned int word = (t & 32) ? (unsigned int)(m >> 32) : (unsigned int)m;
    if (bit == 0) {
      bmp8[r*BMP8_ROWWORDS + iw] = word;
      if (word) atomicAdd(&s_area, __popc(word));
    }
  }
  __syncthreads();
  if (t == 0) wsI[OFF_AREA + g] = s_area;
}

// ---------------- scan: single-wave, compacted active list, shift-free ----------------
__device__ __forceinline__ void loadDet(const uint4* __restrict__ base, int g, int t,
                                        uint4 d[3][2]) {
  const uint4* p = base + g*(BMP8_DETWORDS/4);
  #pragma unroll
  for (int j = 0; j < 3; ++j) {
    int rr = t + j*64; rr = (rr < BMP_ROWS) ? rr : (BMP_ROWS - 1);  // clamp; masked later
    d[j][0] = p[rr*2 + 0];
    d[j][1] = p[rr*2 + 1];
  }
}

__device__ __forceinline__ void processDet(int t, const uint4 d[3][2], unsigned int* occ,
                                           int area, int yb, int q0,
                                           int* __restrict__ accp,
                                           uint4* __restrict__ wb) {
  const int ylo = yb & 0xffff;
  const int rows = (yb >> 16) - ylo;
  unsigned int w[3][8], o[3][8];
  int cnt = 0;
  #pragma unroll
  for (int j = 0; j < 3; ++j) {
    const int rr = t + j*64;
    const bool rv = rr < rows;
    const int rb = (ylo + (rv ? rr : 0)) * OCC_STRIDE + q0;
    unsigned int ww[8] = {d[j][0].x, d[j][0].y, d[j][0].z, d[j][0].w,
                          d[j][1].x, d[j][1].y, d[j][1].z, d[j][1].w};
    #pragma unroll
    for (int i = 0; i < 8; ++i) {
      unsigned int wv = rv ? ww[i] : 0u;
      unsigned int ov = occ[rb + i];        // q0+i <= 22 < OCC_STRIDE: stays in this row
      cnt += __popc(wv & ov);
      w[j][i] = wv; o[j][i] = ov;
    }
  }
  #pragma unroll
  for (int off = 32; off; off >>= 1) cnt += __shfl_xor(cnt, off);
  const bool acc = ((float)cnt / (float)area) < 0.5f;   // area>0 guaranteed (compacted list)
  if (acc) {
    if (t == 0) *accp = 1;
    #pragma unroll
    for (int j = 0; j < 3; ++j) {
      const int rr = t + j*64;
      if (rr < rows) {                      // rows disjoint per lane: no races
        const int rb = (ylo + rr) * OCC_STRIDE + q0;
        #pragma unroll
        for (int i = 0; i < 8; ++i) occ[rb + i] = o[j][i] | w[j][i];
        uint4 n0, n1;
        n0.x = w[j][0] & ~o[j][0];  n0.y = w[j][1] & ~o[j][1];
        n0.z = w[j][2] & ~o[j][2];  n0.w = w[j][3] & ~o[j][3];
        n1.x = w[j][4] & ~o[j][4];  n1.y = w[j][5] & ~o[j][5];
        n1.z = w[j][6] & ~o[j][6];  n1.w = w[j][7] & ~o[j][7];
        wb[rr*2 + 0] = n0;                  // clipped (painted) bits, fire-and-forget
        wb[rr*2 + 1] = n1;
      }
    }
  }
}

__global__ void __launch_bounds__(64) k_scan(int* __restrict__ wsI) {
  const int b = blockIdx.x, t = threadIdx.x;   // 1 wave: lockstep, barrier-free main loop
  __shared__ unsigned int occ[OCC_WORDS];      // 51.2 KB
  __shared__ int s_list[ND], s_area[ND], s_yb[ND], s_q0[ND];
  for (int i = t; i < OCC_WORDS; i += 64) occ[i] = 0u;
  for (int i = t; i < ND; i += 64) {
    s_area[i] = wsI[OFF_AREA + b*ND + i];
    s_yb[i]   = wsI[OFF_YB   + b*ND + i];
    s_q0[i]   = wsI[OFF_QN   + b*ND + i] & 0xffff;
    wsI[OFF_ACC + b*ND + i] = 0;
  }
  __syncthreads();
  int nact = 0;                                 // ordered compaction of area>0 dets
  for (int base = 0; base < ND; base += 64) {
    int i = base + t;
    bool a = (i < ND) && (s_area[i] > 0);
    unsigned long long m = __ballot(a);
    int pos = nact + __popcll(m & ((1ull << t) - 1ull));
    if (a) s_list[pos] = i;
    nact += (int)__popcll(m);
  }
  __syncthreads();
  if (nact == 0) return;
  unsigned int* bmpW = (unsigned int*)wsI + OFF_BMP8 + (size_t)b*ND*BMP8_DETWORDS;
  const uint4* bmp4 = (const uint4*)bmpW;
  int* accB = wsI + OFF_ACC + b*ND;
  uint4 A[3][2], B[3][2];
  loadDet(bmp4, s_list[0], t, A);
  for (int ii = 0; ii < nact; ii += 2) {
    const int gA = s_list[ii];
    const int gB = s_list[(ii+1 < nact) ? (ii+1) : ii];
    loadDet(bmp4, gB, t, B);
    processDet(t, A, occ, s_area[gA], s_yb[gA], s_q0[gA], accB + gA,
               (uint4*)(bmpW + gA*BMP8_DETWORDS));
    const int gN = s_list[(ii+2 < nact) ? (ii+2) : ii];
    loadDet(bmp4, gN, t, A);
    if (ii+1 < nact)
      processDet(t, B, occ, s_area[gB], s_yb[gB], s_q0[gB], accB + gB,
                 (uint4*)(bmpW + gB*BMP8_DETWORDS));
  }
}

// ---------------- stuff: base panoptic image (inst=-1, cat=stuff/void) ----------------
__global__ void k_stuff(const int* __restrict__ wsI, int* __restrict__ out) {
  const int t = threadIdx.x;
  const int pid = blockIdx.x*256 + t;
  const int b = pid >> 18;
  __shared__ int s_cnt[NC];
  if (t < NC) s_cnt[t] = wsI[OFF_COUNTS + b*32 + t];
  __syncthreads();
  int cls = ((const unsigned char*)wsI)[OFF_SEGCLS*4 + pid];
  int cat = (cls >= 2 && s_cnt[cls] > 4096) ? cls + 90 : 0;
  out[pid] = -1;
  out[NB*OH*OW + pid] = cat;
}

// ---------------- paint: expand each accepted det's clipped bitmap ----------------
__global__ void k_paint(const int* __restrict__ wsI, int* __restrict__ out) {
  const int g = blockIdx.x;       // b*ND + sorted k
  if (!wsI[OFF_ACC + g]) return;  // uniform
  const int t = threadIdx.x;      // 256 = 8 words x 32 bits
  const int yb = wsI[OFF_YB + g];
  const int ylo = yb & 0xffff;
  const int rows = (yb >> 16) - ylo;
  const int q0 = wsI[OFF_QN + g] & 0xffff;
  const int val = wsI[OFF_VAL + g];
  const int inst = val & 0xffff, cat = val >> 16;
  const int b = g / ND;
  const unsigned int* bmp = (const unsigned int*)wsI + OFF_BMP8 + g*BMP8_DETWORDS;
  int* __restrict__ outInst = out + b*(OH*OW);
  int* __restrict__ outCat  = out + NB*(OH*OW) + b*(OH*OW);
  const int iw = t >> 5, bit = t & 31;
  const int x = ((q0 + iw) << 5) + bit;
  if (x >= OW) return;            // pad words are zero; skip their lanes
  for (int r = 0; r < rows; ++r) {
    unsigned int wv = bmp[r*BMP8_ROWWORDS + iw];
    if ((wv >> bit) & 1u) {
      int idx = (ylo + r)*OW + x;
      outInst[idx] = inst;
      outCat [idx] = cat;
    }
  }
}

extern "C" void kernel_launch(void* const* d_in, const int* in_sizes, int n_in,
                              void* d_out, int out_size, void* d_ws, size_t ws_size,
                              hipStream_t stream) {
  const float* boxes   = (const float*)d_in[0];
  const int*   classes = (const int*)d_in[1];
  const float* scores  = (const float*)d_in[2];
  const float* dmasks  = (const float*)d_in[3];
  const float* seg     = (const float*)d_in[4];
  int* wsI = (int*)d_ws;
  int* out = (int*)d_out;

  k_prep <<<NB, 128, 0, stream>>>(boxes, classes, scores, wsI);
  k_seg  <<<(NB*OH*OW)/256, 256, 0, stream>>>(seg, wsI);
  k_mask <<<NB*ND, 256, 0, stream>>>(dmasks, wsI);
  k_scan <<<NB, 64, 0, stream>>>(wsI);
  k_stuff<<<(NB*OH*OW)/256, 256, 0, stream>>>(wsI, out);
  k_paint<<<NB*ND, 256, 0, stream>>>(wsI, out);
}